// Round 1
// 597.727 us; speedup vs baseline: 1.0028x; 1.0028x over previous
//
#include <hip/hip_runtime.h>
#include <cstdint>
#include <cstddef>

#define B_   64
#define T_   256
#define DIN_ 128
#define H_   256
#define G3_  768   // 3*H

typedef _Float16 f16x8 __attribute__((ext_vector_type(8)));
typedef float    f32x4 __attribute__((ext_vector_type(4)));

#define MFMA(a, b, c) __builtin_amdgcn_mfma_f32_16x16x32_f16((a), (b), (c), 0, 0, 0)

// ---------- helpers ----------
__device__ __forceinline__ unsigned short f2h(float f) {
  _Float16 h = (_Float16)f;              // v_cvt_f16_f32 (RNE)
  return __builtin_bit_cast(unsigned short, h);
}

// ---------- prep ----------
// Wreg layout for MFMA gru (512 threads/block):
//   frag index fi = (g*2+uti)*8 + kf   (g=gate 0..2, uti=u-tile 0..1, kf=0..7)
//   thread tid: wave w=tid>>6, lane l=tid&63; output u=(2w+uti)*16+(l&15)
//   B-frag dword d holds fp16 pair (k, k+1), k = kf*32 + (l>>4)*8 + 2d
//   Wreg dword m = (fi*512 + tid)*4 + d  -> coalesced uint4 loads W4[fi*512+tid]
__global__ __launch_bounds__(256) void prep_kernel(
    const float* __restrict__ W_ih, const float* __restrict__ W_hh,
    const float* __restrict__ W_mz, const float* __restrict__ W_mx,
    const float* __restrict__ W_pz, const float* __restrict__ W_cx,
    float* __restrict__ WT_ih, float* __restrict__ WheadT,
    unsigned* __restrict__ Wreg) {
  int i = blockIdx.x * 256 + threadIdx.x;
  if (i < 98304) {                       // WT_ih[k*768+g] = W_ih[g*128+k]
    int k = i / 768, g = i % 768;
    WT_ih[i] = W_ih[g * 128 + k];
  } else if (i < 98304 + 24576) {        // WheadT[c*256+k]
    int j = i - 98304;
    int c = j >> 8, k = j & 255;
    float v;
    if (c < 8)       v = W_mz[c * 256 + k];
    else if (c < 16) v = W_mx[(c - 8) * 256 + k];
    else if (c < 32) v = W_pz[(c - 16) * 256 + k];
    else             v = W_cx[(c - 32) * 256 + k];
    WheadT[j] = v;
  } else {                               // W_hh fp16 B-frag repack
    int m = i - 122880;                  // 0..98303
    int c = m & 3, n = m >> 2;           // c = frag dword d
    int tid = n & 511, j4 = n >> 9;      // j4 = fi in [0,48)
    int g   = j4 >> 4;                   // gate 0..2
    int rem = j4 & 15;
    int uti = rem >> 3, kf = rem & 7;
    int wv = tid >> 6, l = tid & 63;
    int u = (2 * wv + uti) * 16 + (l & 15);
    int k = kf * 32 + ((l >> 4) << 3) + 2 * c;
    int row = g * 256 + u;
    unsigned short lo = f2h(W_hh[row * 256 + k]);
    unsigned short hi = f2h(W_hh[row * 256 + k + 1]);
    Wreg[m] = ((unsigned)hi << 16) | (unsigned)lo;
  }
}

// ---------- x_proj = y @ W_ih^T + b_ih (+ b_hh folded for r,z gates) ----------
__global__ __launch_bounds__(256) void xproj_kernel(
    const float* __restrict__ y, const float* __restrict__ WT_ih,
    const float* __restrict__ b_ih, const float* __restrict__ b_hh,
    float* __restrict__ xp) {
  __shared__ float ylds[64][132];
  int tid = threadIdx.x;
  int row0 = blockIdx.x * 64;
  const float4* y4 = (const float4*)(y + (size_t)row0 * DIN_);
#pragma unroll
  for (int i = 0; i < 8; ++i) {
    int idx = i * 256 + tid;             // 2048 float4 = 64x128
    float4 v = y4[idx];
    int r = idx >> 5, c4 = (idx & 31) * 4;
    ylds[r][c4 + 0] = v.x; ylds[r][c4 + 1] = v.y;
    ylds[r][c4 + 2] = v.z; ylds[r][c4 + 3] = v.w;
  }
  __syncthreads();
  int tx = tid & 15, ty = tid >> 4;      // thread: 4 rows x 8 cols
  for (int c = 0; c < 6; ++c) {
    int col0 = c * 128 + tx * 8;
    float acc[4][8];
#pragma unroll
    for (int a = 0; a < 4; ++a)
#pragma unroll
      for (int b = 0; b < 8; ++b) acc[a][b] = 0.f;
#pragma unroll 4
    for (int k = 0; k < 128; ++k) {
      float4 w0 = *(const float4*)&WT_ih[k * 768 + col0];
      float4 w1 = *(const float4*)&WT_ih[k * 768 + col0 + 4];
      float a0 = ylds[ty * 4 + 0][k], a1 = ylds[ty * 4 + 1][k];
      float a2 = ylds[ty * 4 + 2][k], a3 = ylds[ty * 4 + 3][k];
      acc[0][0] += a0 * w0.x; acc[0][1] += a0 * w0.y; acc[0][2] += a0 * w0.z; acc[0][3] += a0 * w0.w;
      acc[0][4] += a0 * w1.x; acc[0][5] += a0 * w1.y; acc[0][6] += a0 * w1.z; acc[0][7] += a0 * w1.w;
      acc[1][0] += a1 * w0.x; acc[1][1] += a1 * w0.y; acc[1][2] += a1 * w0.z; acc[1][3] += a1 * w0.w;
      acc[1][4] += a1 * w1.x; acc[1][5] += a1 * w1.y; acc[1][6] += a1 * w1.z; acc[1][7] += a1 * w1.w;
      acc[2][0] += a2 * w0.x; acc[2][1] += a2 * w0.y; acc[2][2] += a2 * w0.z; acc[2][3] += a2 * w0.w;
      acc[2][4] += a2 * w1.x; acc[2][5] += a2 * w1.y; acc[2][6] += a2 * w1.z; acc[2][7] += a2 * w1.w;
      acc[3][0] += a3 * w0.x; acc[3][1] += a3 * w0.y; acc[3][2] += a3 * w0.z; acc[3][3] += a3 * w0.w;
      acc[3][4] += a3 * w1.x; acc[3][5] += a3 * w1.y; acc[3][6] += a3 * w1.z; acc[3][7] += a3 * w1.w;
    }
    float4 b0 = *(const float4*)&b_ih[col0];
    float4 b1 = *(const float4*)&b_ih[col0 + 4];
    if (c < 4) {                         // fold b_hh into r,z gate columns (<512)
      float4 h0 = *(const float4*)&b_hh[col0];
      float4 h1 = *(const float4*)&b_hh[col0 + 4];
      b0.x += h0.x; b0.y += h0.y; b0.z += h0.z; b0.w += h0.w;
      b1.x += h1.x; b1.y += h1.y; b1.z += h1.z; b1.w += h1.w;
    }
#pragma unroll
    for (int a = 0; a < 4; ++a) {
      int row = row0 + ty * 4 + a;
      float4 o0, o1;
      o0.x = acc[a][0] + b0.x; o0.y = acc[a][1] + b0.y; o0.z = acc[a][2] + b0.z; o0.w = acc[a][3] + b0.w;
      o1.x = acc[a][4] + b1.x; o1.y = acc[a][5] + b1.y; o1.z = acc[a][6] + b1.z; o1.w = acc[a][7] + b1.w;
      *(float4*)&xp[(size_t)row * G3_ + col0] = o0;
      *(float4*)&xp[(size_t)row * G3_ + col0 + 4] = o1;
    }
  }
}

// ---------- GRU recurrence via MFMA: 64 blocks x 512 threads ----------
// Wave w owns outputs [32w, 32w+32) as two 16-wide u-tiles. B-operand = h
// (column-replicated), A-operand = h-frag, so D columns all hold the same
// pre-activation; lane l owns outputs u0 = 32w+(l&15) and u1 = u0+16.
// One barrier per step (double-buffered fp16 h in LDS).
#define GRU_STEP(PAR, xr0, xz0, xn0, xr1, xz1, xn1,                            \
                 nxr0, nxz0, nxn0, nxr1, nxz1, nxn1)                           \
  {                                                                            \
    asm volatile("" ::: "memory"); /* forbid wf[] remat from Wreg */           \
    const int tc = t + PAR;                                                    \
    const float* xq = xpb + (size_t)(tc + 1) * G3_; /* prefetch t+1 */         \
    nxr0 = xq[u0]; nxz0 = xq[256 + u0]; nxn0 = xq[512 + u0];                   \
    nxr1 = xq[u1]; nxz1 = xq[256 + u1]; nxn1 = xq[512 + u1];                   \
    uint4 hq0 = h4[PAR * 32 + g16];                                            \
    f16x8 hf0 = __builtin_bit_cast(f16x8, hq0);                                \
    f32x4 aR0 = MFMA(hf0, wf[0],  z4);  f32x4 aR1 = MFMA(hf0, wf[8],  z4);     \
    f32x4 aZ0 = MFMA(hf0, wf[16], z4);  f32x4 aZ1 = MFMA(hf0, wf[24], z4);     \
    f32x4 aN0 = MFMA(hf0, wf[32], z4);  f32x4 aN1 = MFMA(hf0, wf[40], z4);     \
    _Pragma("unroll")                                                          \
    for (int kf = 1; kf < 8; ++kf) {                                           \
      uint4 hq = h4[PAR * 32 + kf * 4 + g16];                                  \
      f16x8 hk = __builtin_bit_cast(f16x8, hq);                                \
      aR0 = MFMA(hk, wf[kf],      aR0); aR1 = MFMA(hk, wf[8 + kf],  aR1);      \
      aZ0 = MFMA(hk, wf[16 + kf], aZ0); aZ1 = MFMA(hk, wf[24 + kf], aZ1);      \
      aN0 = MFMA(hk, wf[32 + kf], aN0); aN1 = MFMA(hk, wf[40 + kf], aN1);      \
    }                                                                          \
    float pr0 = aR0[0] + xr0, pz0 = aZ0[0] + xz0, pn0 = aN0[0] + bhn0;         \
    float pr1 = aR1[0] + xr1, pz1 = aZ1[0] + xz1, pn1 = aN1[0] + bhn1;         \
    float r0 = 1.f / (1.f + __expf(-pr0)), r1 = 1.f / (1.f + __expf(-pr1));    \
    float q0 = 1.f / (1.f + __expf(-pz0)), q1 = 1.f / (1.f + __expf(-pz1));    \
    float a0 = xn0 + r0 * pn0, a1 = xn1 + r1 * pn1;                            \
    a0 = fminf(15.f, fmaxf(-15.f, a0)); a1 = fminf(15.f, fmaxf(-15.f, a1));    \
    float e0 = __expf(2.f * a0), e1 = __expf(2.f * a1);                        \
    float n0 = (e0 - 1.f) / (e0 + 1.f), n1 = (e1 - 1.f) / (e1 + 1.f);          \
    float h0n = (1.f - q0) * n0 + q0 * hold0;                                  \
    float h1n = (1.f - q1) * n1 + q1 * hold1;                                  \
    hold0 = h0n; hold1 = h1n;          /* exact fp32 state, all lanes */       \
    if ((l >> 4) == 0) {               /* one writer group per wave */         \
      encb[tc * 256 + u0] = h0n;  encb[tc * 256 + u1] = h1n;                   \
      h16[PAR ^ 1][u0] = f2h(h0n); h16[PAR ^ 1][u1] = f2h(h1n);                \
    }                                                                          \
    __syncthreads();                                                           \
  }

__global__ __launch_bounds__(512) __attribute__((amdgpu_waves_per_eu(2, 2)))
void gru_kernel(
    const float* __restrict__ xp, const unsigned* Wreg,
    const float* __restrict__ b_hh, float* enc) {
  int tid = threadIdx.x;
  int b = blockIdx.x;
  int w = tid >> 6;
  int l = tid & 63;
  int g16 = l >> 4;                      // 16-lane group = K-chunk owner
  int u0 = w * 32 + (l & 15);
  int u1 = u0 + 16;
  __shared__ alignas(16) unsigned short h16[2][256];   // double-buffered h

  f16x8 wf[48];                          // W_hh B-frags, register-resident
  const uint4* W4 = (const uint4*)Wreg;
#pragma unroll
  for (int fi = 0; fi < 48; ++fi) {
    uint4 q = W4[fi * 512 + tid];        // coalesced dwordx4, once
    wf[fi] = __builtin_bit_cast(f16x8, q);
  }
  if (tid < 32) {                        // h0 = 0 (buffer 0)
    uint4 z = {0u, 0u, 0u, 0u};
    ((uint4*)h16)[tid] = z;
  }
  const float* xpb = xp + (size_t)b * (T_ * G3_);
  float* encb = enc + (size_t)b * (T_ * H_);
  float bhn0 = b_hh[512 + u0], bhn1 = b_hh[512 + u1];
  float hold0 = 0.f, hold1 = 0.f;
  const f32x4 z4 = {0.f, 0.f, 0.f, 0.f};
  // t=0 xp values (r,z already include b_ih + b_hh via xproj fold)
  float xrA0 = xpb[u0], xzA0 = xpb[256 + u0], xnA0 = xpb[512 + u0];
  float xrA1 = xpb[u1], xzA1 = xpb[256 + u1], xnA1 = xpb[512 + u1];
  __syncthreads();
  const uint4* h4 = (const uint4*)h16;
  float xrB0, xzB0, xnB0, xrB1, xzB1, xnB1;
  for (int t = 0; t < T_; t += 2) {
    GRU_STEP(0, xrA0, xzA0, xnA0, xrA1, xzA1, xnA1,
                xrB0, xzB0, xnB0, xrB1, xzB1, xnB1)
    GRU_STEP(1, xrB0, xzB0, xnB0, xrB1, xzB1, xnB1,
                xrA0, xzA0, xnA0, xrA1, xzA1, xnA1)
  }
}

// ---------- heads (0-511) + upper-half chol zero (512-703) + anchor (704-831) ---
// heads writes mean_x WITHOUT the anchor subtraction (applied in chol_fin).
__global__ __launch_bounds__(384) void heads_kernel(
    const float* __restrict__ enc, const float* __restrict__ WheadT,
    const float* __restrict__ b_mz, const float* __restrict__ b_mx,
    const float* __restrict__ b_pz, const float* __restrict__ b_cx,
    float* __restrict__ out_meanz, float* __restrict__ out_meanx,
    float* __restrict__ out_covx, float* __restrict__ stage,
    float4* __restrict__ chol4, float* __restrict__ anchor,
    const float* __restrict__ W_mx) {
  int tid = threadIdx.x;
  if (blockIdx.x >= 704) {               // ---- anchor: block = (b,d)
    __shared__ float red[4];
    int bid = blockIdx.x - 704;
    int b = bid >> 1, d = bid & 1;
    if (tid < 256) {
      float v = enc[(size_t)b * (T_ * H_) + tid] * W_mx[d * 256 + tid];
#pragma unroll
      for (int off = 32; off >= 1; off >>= 1) v += __shfl_down(v, off, 64);
      if ((tid & 63) == 0) red[tid >> 6] = v;
    }
    __syncthreads();
    if (tid == 0)
      anchor[b * 2 + d] = b_mx[d] + ((red[0] + red[1]) + (red[2] + red[3]));
    return;
  }
  if (blockIdx.x >= 512) {               // ---- zero chol floats [16777216, 33554432)
    float4* cz = chol4 + 4194304;
    int idx = (blockIdx.x - 512) * 384 + tid;
    float4 z = {0.f, 0.f, 0.f, 0.f};
    for (; idx < 4194304; idx += 192 * 384) cz[idx] = z;
    return;
  }
  __shared__ float el[32 * 256];         // 32 KB
  int row0 = blockIdx.x * 32;
  const float4* e4 = (const float4*)(enc + (size_t)row0 * 256);
  float4* el4 = (float4*)el;
#pragma unroll
  for (int i = 0; i < 6; ++i) {
    int idx = i * 384 + tid;             // 2048 float4 = 32x64
    if (idx < 2048) el4[idx] = e4[idx];
  }
  __syncthreads();
  int rg = tid / 96, c = tid - rg * 96;  // rg in [0,4), c in [0,96)
  const float4* Wc = (const float4*)(WheadT + c * 256);
  float acc[8];
#pragma unroll
  for (int r = 0; r < 8; ++r) acc[r] = 0.f;
  for (int k4 = 0; k4 < 64; ++k4) {
    float4 w4 = Wc[k4];
#pragma unroll
    for (int r = 0; r < 8; ++r) {
      float4 ev = el4[(rg * 8 + r) * 64 + k4];
      acc[r] += w4.x * ev.x; acc[r] += w4.y * ev.y;
      acc[r] += w4.z * ev.z; acc[r] += w4.w * ev.w;
    }
  }
#pragma unroll
  for (int r = 0; r < 8; ++r) {
    int row = row0 + rg * 8 + r;
    float a_ = acc[r];
    if (c < 8) {
      out_meanz[(size_t)row * 8 + c] = a_ + b_mz[c];
    } else if (c < 16) {
      int d = c - 8;
      out_meanx[(size_t)row * 8 + d] = a_ + b_mx[d];   // anchor applied later
    } else if (c < 32) {
      int d = c - 16;
      float v = a_ + b_pz[d];
      if (d < 8)                          // diag: softplus (stable)
        v = (v > 0.f) ? (v + log1pf(__expf(-v))) : log1pf(__expf(v));
      stage[(size_t)row * 16 + d] = v;
    } else {
      int d = c - 32;
      out_covx[(size_t)row * 64 + d] = a_ + b_cx[d];
    }
  }
}

// ---------- final: fused zero+scatter lower chol, upper scatter, mean_x fix ----
__global__ __launch_bounds__(256) void chol_fin(
    const float* __restrict__ stage, float4* __restrict__ chol,
    const float* __restrict__ anchor, float* __restrict__ mean_x) {
  int i = blockIdx.x * 256 + threadIdx.x;
  int stride = gridDim.x * 256;
  for (; i < 4358144; i += stride) {
    if (i < 4194304) {                  // lower half: d = 0..3, fused zero+scatter
      int d = i >> 20;
      int bt = (i >> 6) & 16383;
      int t = bt & 255;
      int lane = i & 63;
      float vd = 0.f, vo = 0.f;
      if ((t >> 2) == lane)       vd = stage[bt * 16 + d];
      if (((t + 1) >> 2) == lane) vo = stage[bt * 16 + 8 + d];
      int te = t & 3, oe = (t + 1) & 3;
      float4 v;
      v.x = (te == 0 ? vd : 0.f) + (oe == 0 ? vo : 0.f);
      v.y = (te == 1 ? vd : 0.f) + (oe == 1 ? vo : 0.f);
      v.z = (te == 2 ? vd : 0.f) + (oe == 2 ? vo : 0.f);
      v.w = (te == 3 ? vd : 0.f) + (oe == 3 ? vo : 0.f);
      chol[i] = v;
    } else if (i < 4325376) {           // upper half: scatter d = 4..7
      int j = i - 4194304;              // [0, 131072)
      int bt = j >> 3, q = j & 7;
      int bb = bt >> 8, tt = bt & 255;
      int d = 4 + (q & 3);
      float* ch = (float*)chol;
      if (q < 4) {
        ch[(((size_t)d * 64 + bb) * 256 + tt) * 256 + tt] = stage[bt * 16 + d];
      } else if (tt < 255) {
        ch[(((size_t)d * 64 + bb) * 256 + tt) * 256 + tt + 1] = stage[bt * 16 + 8 + d];
      }
    } else {                            // deferred anchor subtraction on mean_x
      int j2 = i - 4325376;             // [0, 32768)
      int row = j2 >> 1, d = j2 & 1;
      mean_x[(size_t)row * 8 + d] -= anchor[(row >> 8) * 2 + d];
    }
  }
}

extern "C" void kernel_launch(void* const* d_in, const int* in_sizes, int n_in,
                              void* d_out, int out_size, void* d_ws, size_t ws_size,
                              hipStream_t stream) {
  const float* y    = (const float*)d_in[0];
  const float* W_ih = (const float*)d_in[1];
  const float* W_hh = (const float*)d_in[2];
  const float* b_ih = (const float*)d_in[3];
  const float* b_hh = (const float*)d_in[4];
  const float* W_mz = (const float*)d_in[5];
  const float* b_mz = (const float*)d_in[6];
  const float* W_mx = (const float*)d_in[7];
  const float* b_mx = (const float*)d_in[8];
  const float* W_pz = (const float*)d_in[9];
  const float* b_pz = (const float*)d_in[10];
  const float* W_cx = (const float*)d_in[11];
  const float* b_cx = (const float*)d_in[12];

  float* out    = (float*)d_out;
  float* mean_z = out;                    // [64,256,8]
  float* chol   = out + 131072;           // [8,64,256,256]
  float* mean_x = out + 33685504;         // [16384,8]
  float* cov_x  = out + 33816576;         // [16384,8,8]

  float* ws      = (float*)d_ws;
  float* WT_ih   = ws;                    // 98304
  float* WheadT  = ws + 98304;            // 24576
  unsigned* Wreg = (unsigned*)(ws + 122880); // 98304
  float* anchor  = ws + 221184;           // 128
  float* stage   = ws + 221312;           // 262144

  // large scratch inside the chol LOWER half (rewritten by chol_fin at end);
  // upper half [16777216,33554432) is zeroed during the heads launch.
  float* xp  = chol;                      // 12582912 floats
  float* enc = chol + 12582912;           // 4194304 floats (ends at 16777216)

  prep_kernel<<<864, 256, 0, stream>>>(W_ih, W_hh, W_mz, W_mx, W_pz, W_cx,
                                       WT_ih, WheadT, Wreg);
  xproj_kernel<<<256, 256, 0, stream>>>(y, WT_ih, b_ih, b_hh, xp);
  gru_kernel<<<64, 512, 0, stream>>>(xp, Wreg, b_hh, enc);
  heads_kernel<<<832, 384, 0, stream>>>(enc, WheadT, b_mz, b_mx, b_pz, b_cx,
                                        mean_z, mean_x, cov_x, stage,
                                        (float4*)chol, anchor, W_mx);
  chol_fin<<<4096, 256, 0, stream>>>(stage, (float4*)chol, anchor, mean_x);
}

// Round 2
// 557.868 us; speedup vs baseline: 1.0744x; 1.0714x over previous
//
#include <hip/hip_runtime.h>
#include <cstdint>
#include <cstddef>

#define B_   64
#define T_   256
#define DIN_ 128
#define H_   256
#define G3_  768   // 3*H

typedef _Float16 f16x8 __attribute__((ext_vector_type(8)));
typedef float    f32x4 __attribute__((ext_vector_type(4)));

#define MFMA(a, b, c) __builtin_amdgcn_mfma_f32_16x16x32_f16((a), (b), (c), 0, 0, 0)

// ---------- helpers ----------
__device__ __forceinline__ unsigned short f2h(float f) {
  _Float16 h = (_Float16)f;              // v_cvt_f16_f32 (RNE)
  return __builtin_bit_cast(unsigned short, h);
}

// ---------- prep ----------
// Wreg layout for MFMA gru (512 threads/block):
//   frag index fi = (g*2+uti)*8 + kf   (g=gate 0..2, uti=u-tile 0..1, kf=0..7)
//   thread tid: wave w=tid>>6, lane l=tid&63; output u=(2w+uti)*16+(l&15)
//   B-frag dword d holds fp16 pair (k, k+1), k = kf*32 + (l>>4)*8 + 2d
//   Wreg dword m = (fi*512 + tid)*4 + d  -> coalesced uint4 loads W4[fi*512+tid]
__global__ __launch_bounds__(256) void prep_kernel(
    const float* __restrict__ W_ih, const float* __restrict__ W_hh,
    const float* __restrict__ W_mz, const float* __restrict__ W_mx,
    const float* __restrict__ W_pz, const float* __restrict__ W_cx,
    float* __restrict__ WT_ih, float* __restrict__ WheadT,
    unsigned* __restrict__ Wreg) {
  int i = blockIdx.x * 256 + threadIdx.x;
  if (i < 98304) {                       // WT_ih[k*768+g] = W_ih[g*128+k]
    int k = i / 768, g = i % 768;
    WT_ih[i] = W_ih[g * 128 + k];
  } else if (i < 98304 + 24576) {        // WheadT[c*256+k]
    int j = i - 98304;
    int c = j >> 8, k = j & 255;
    float v;
    if (c < 8)       v = W_mz[c * 256 + k];
    else if (c < 16) v = W_mx[(c - 8) * 256 + k];
    else if (c < 32) v = W_pz[(c - 16) * 256 + k];
    else             v = W_cx[(c - 32) * 256 + k];
    WheadT[j] = v;
  } else {                               // W_hh fp16 B-frag repack
    int m = i - 122880;                  // 0..98303
    int c = m & 3, n = m >> 2;           // c = frag dword d
    int tid = n & 511, j4 = n >> 9;      // j4 = fi in [0,48)
    int g   = j4 >> 4;                   // gate 0..2
    int rem = j4 & 15;
    int uti = rem >> 3, kf = rem & 7;
    int wv = tid >> 6, l = tid & 63;
    int u = (2 * wv + uti) * 16 + (l & 15);
    int k = kf * 32 + ((l >> 4) << 3) + 2 * c;
    int row = g * 256 + u;
    unsigned short lo = f2h(W_hh[row * 256 + k]);
    unsigned short hi = f2h(W_hh[row * 256 + k + 1]);
    Wreg[m] = ((unsigned)hi << 16) | (unsigned)lo;
  }
}

// ---------- x_proj = y @ W_ih^T + b_ih (+ b_hh folded for r,z gates) ----------
// 512 blocks: blockIdx>>1 selects 64-row stripe, blockIdx&1 selects 3 of 6 col-tiles.
__global__ __launch_bounds__(256) void xproj_kernel(
    const float* __restrict__ y, const float* __restrict__ WT_ih,
    const float* __restrict__ b_ih, const float* __restrict__ b_hh,
    float* __restrict__ xp) {
  __shared__ float ylds[64][132];
  int tid = threadIdx.x;
  int row0 = (blockIdx.x >> 1) * 64;
  int c0 = (blockIdx.x & 1) * 3;
  const float4* y4 = (const float4*)(y + (size_t)row0 * DIN_);
#pragma unroll
  for (int i = 0; i < 8; ++i) {
    int idx = i * 256 + tid;             // 2048 float4 = 64x128
    float4 v = y4[idx];
    int r = idx >> 5, c4 = (idx & 31) * 4;
    ylds[r][c4 + 0] = v.x; ylds[r][c4 + 1] = v.y;
    ylds[r][c4 + 2] = v.z; ylds[r][c4 + 3] = v.w;
  }
  __syncthreads();
  int tx = tid & 15, ty = tid >> 4;      // thread: 4 rows x 8 cols
  for (int c = c0; c < c0 + 3; ++c) {
    int col0 = c * 128 + tx * 8;
    float acc[4][8];
#pragma unroll
    for (int a = 0; a < 4; ++a)
#pragma unroll
      for (int b = 0; b < 8; ++b) acc[a][b] = 0.f;
#pragma unroll 4
    for (int k = 0; k < 128; ++k) {
      float4 w0 = *(const float4*)&WT_ih[k * 768 + col0];
      float4 w1 = *(const float4*)&WT_ih[k * 768 + col0 + 4];
      float a0 = ylds[ty * 4 + 0][k], a1 = ylds[ty * 4 + 1][k];
      float a2 = ylds[ty * 4 + 2][k], a3 = ylds[ty * 4 + 3][k];
      acc[0][0] += a0 * w0.x; acc[0][1] += a0 * w0.y; acc[0][2] += a0 * w0.z; acc[0][3] += a0 * w0.w;
      acc[0][4] += a0 * w1.x; acc[0][5] += a0 * w1.y; acc[0][6] += a0 * w1.z; acc[0][7] += a0 * w1.w;
      acc[1][0] += a1 * w0.x; acc[1][1] += a1 * w0.y; acc[1][2] += a1 * w0.z; acc[1][3] += a1 * w0.w;
      acc[1][4] += a1 * w1.x; acc[1][5] += a1 * w1.y; acc[1][6] += a1 * w1.z; acc[1][7] += a1 * w1.w;
      acc[2][0] += a2 * w0.x; acc[2][1] += a2 * w0.y; acc[2][2] += a2 * w0.z; acc[2][3] += a2 * w0.w;
      acc[2][4] += a2 * w1.x; acc[2][5] += a2 * w1.y; acc[2][6] += a2 * w1.z; acc[2][7] += a2 * w1.w;
      acc[3][0] += a3 * w0.x; acc[3][1] += a3 * w0.y; acc[3][2] += a3 * w0.z; acc[3][3] += a3 * w0.w;
      acc[3][4] += a3 * w1.x; acc[3][5] += a3 * w1.y; acc[3][6] += a3 * w1.z; acc[3][7] += a3 * w1.w;
    }
    float4 b0 = *(const float4*)&b_ih[col0];
    float4 b1 = *(const float4*)&b_ih[col0 + 4];
    if (c < 4) {                         // fold b_hh into r,z gate columns (<512)
      float4 h0 = *(const float4*)&b_hh[col0];
      float4 h1 = *(const float4*)&b_hh[col0 + 4];
      b0.x += h0.x; b0.y += h0.y; b0.z += h0.z; b0.w += h0.w;
      b1.x += h1.x; b1.y += h1.y; b1.z += h1.z; b1.w += h1.w;
    }
#pragma unroll
    for (int a = 0; a < 4; ++a) {
      int row = row0 + ty * 4 + a;
      float4 o0, o1;
      o0.x = acc[a][0] + b0.x; o0.y = acc[a][1] + b0.y; o0.z = acc[a][2] + b0.z; o0.w = acc[a][3] + b0.w;
      o1.x = acc[a][4] + b1.x; o1.y = acc[a][5] + b1.y; o1.z = acc[a][6] + b1.z; o1.w = acc[a][7] + b1.w;
      *(float4*)&xp[(size_t)row * G3_ + col0] = o0;
      *(float4*)&xp[(size_t)row * G3_ + col0 + 4] = o1;
    }
  }
}

// ---------- GRU recurrence via MFMA: blocks 0-63; blocks 64-255 zero chol upper --
// Wave w owns outputs [32w, 32w+32) as two 16-wide u-tiles. B-operand = W frags
// (register-resident), A-operand = h replicated; lane l owns outputs
// u0 = 32w+(l&15), u1 = u0+16. One barrier per step (double-buffered fp16 h).
// Pointwise ordered so r/z sigmoids never wait on the N-gate accumulators.
#define GRU_STEP(PAR, xr0, xz0, xn0, xr1, xz1, xn1,                            \
                 nxr0, nxz0, nxn0, nxr1, nxz1, nxn1)                           \
  {                                                                            \
    asm volatile("" ::: "memory"); /* forbid wf[] remat from Wreg */           \
    const int tc = t + PAR;                                                    \
    const float* xq = xpb + (size_t)(tc + 1) * G3_; /* prefetch t+1 */         \
    nxr0 = xq[u0]; nxz0 = xq[256 + u0]; nxn0 = xq[512 + u0];                   \
    nxr1 = xq[u1]; nxz1 = xq[256 + u1]; nxn1 = xq[512 + u1];                   \
    uint4 hq0 = h4[PAR * 32 + g16];                                            \
    f16x8 hf0 = __builtin_bit_cast(f16x8, hq0);                                \
    f32x4 aR0 = MFMA(hf0, wf[0],  z4);  f32x4 aR1 = MFMA(hf0, wf[8],  z4);     \
    f32x4 aZ0 = MFMA(hf0, wf[16], z4);  f32x4 aZ1 = MFMA(hf0, wf[24], z4);     \
    f32x4 aN0 = MFMA(hf0, wf[32], z4);  f32x4 aN1 = MFMA(hf0, wf[40], z4);     \
    _Pragma("unroll")                                                          \
    for (int kf = 1; kf < 8; ++kf) {                                           \
      uint4 hq = h4[PAR * 32 + kf * 4 + g16];                                  \
      f16x8 hk = __builtin_bit_cast(f16x8, hq);                                \
      aR0 = MFMA(hk, wf[kf],      aR0); aR1 = MFMA(hk, wf[8 + kf],  aR1);      \
      aZ0 = MFMA(hk, wf[16 + kf], aZ0); aZ1 = MFMA(hk, wf[24 + kf], aZ1);      \
      aN0 = MFMA(hk, wf[32 + kf], aN0); aN1 = MFMA(hk, wf[40 + kf], aN1);      \
    }                                                                          \
    /* r,z path first: touches only aR/aZ so exp runs under N MFMAs */         \
    float pr0 = aR0[0] + xr0, pr1 = aR1[0] + xr1;                              \
    float pz0 = aZ0[0] + xz0, pz1 = aZ1[0] + xz1;                              \
    float r0 = 1.f / (1.f + __expf(-pr0)), r1 = 1.f / (1.f + __expf(-pr1));    \
    float q0 = 1.f / (1.f + __expf(-pz0)), q1 = 1.f / (1.f + __expf(-pz1));    \
    float zh0 = q0 * hold0, zh1 = q1 * hold1;                                  \
    float om0 = 1.f - q0,   om1 = 1.f - q1;                                    \
    float pn0 = aN0[0] + bhn0, pn1 = aN1[0] + bhn1;                            \
    float a0 = xn0 + r0 * pn0, a1 = xn1 + r1 * pn1;                            \
    a0 = fminf(15.f, fmaxf(-15.f, a0)); a1 = fminf(15.f, fmaxf(-15.f, a1));    \
    float e0 = __expf(2.f * a0), e1 = __expf(2.f * a1);                        \
    float n0 = (e0 - 1.f) / (e0 + 1.f), n1 = (e1 - 1.f) / (e1 + 1.f);          \
    float h0n = om0 * n0 + zh0;                                                \
    float h1n = om1 * n1 + zh1;                                                \
    hold0 = h0n; hold1 = h1n;          /* exact fp32 state, all lanes */       \
    if ((l >> 4) == 0) {               /* one writer group per wave */         \
      encb[tc * 256 + u0] = h0n;  encb[tc * 256 + u1] = h1n;                   \
      h16[PAR ^ 1][u0] = f2h(h0n); h16[PAR ^ 1][u1] = f2h(h1n);                \
    }                                                                          \
    __syncthreads();                                                           \
  }

__global__ __launch_bounds__(512) __attribute__((amdgpu_waves_per_eu(2, 2)))
void gru_kernel(
    const float* __restrict__ xp, const unsigned* Wreg,
    const float* __restrict__ b_hh, float* enc, float4* __restrict__ cholU) {
  int tid = threadIdx.x;
  int b = blockIdx.x;
  if (b >= 64) {                         // ---- tail blocks: zero chol upper half
    float4 zz = {0.f, 0.f, 0.f, 0.f};    //      (concurrent with the recurrence)
    int idx = (b - 64) * 512 + tid;      // 192*512 = 98304 threads
    for (; idx < 4194304; idx += 98304) cholU[idx] = zz;
    return;
  }
  int w = tid >> 6;
  int l = tid & 63;
  int g16 = l >> 4;                      // 16-lane group = K-chunk owner
  int u0 = w * 32 + (l & 15);
  int u1 = u0 + 16;
  __shared__ alignas(16) unsigned short h16[2][256];   // double-buffered h

  f16x8 wf[48];                          // W_hh B-frags, register-resident
  const uint4* W4 = (const uint4*)Wreg;
#pragma unroll
  for (int fi = 0; fi < 48; ++fi) {
    uint4 q = W4[fi * 512 + tid];        // coalesced dwordx4, once
    wf[fi] = __builtin_bit_cast(f16x8, q);
  }
  if (tid < 32) {                        // h0 = 0 (buffer 0)
    uint4 z = {0u, 0u, 0u, 0u};
    ((uint4*)h16)[tid] = z;
  }
  const float* xpb = xp + (size_t)b * (T_ * G3_);
  float* encb = enc + (size_t)b * (T_ * H_);
  float bhn0 = b_hh[512 + u0], bhn1 = b_hh[512 + u1];
  float hold0 = 0.f, hold1 = 0.f;
  const f32x4 z4 = {0.f, 0.f, 0.f, 0.f};
  // t=0 xp values (r,z already include b_ih + b_hh via xproj fold)
  float xrA0 = xpb[u0], xzA0 = xpb[256 + u0], xnA0 = xpb[512 + u0];
  float xrA1 = xpb[u1], xzA1 = xpb[256 + u1], xnA1 = xpb[512 + u1];
  __syncthreads();
  const uint4* h4 = (const uint4*)h16;
  float xrB0, xzB0, xnB0, xrB1, xzB1, xnB1;
  for (int t = 0; t < T_; t += 2) {
    GRU_STEP(0, xrA0, xzA0, xnA0, xrA1, xzA1, xnA1,
                xrB0, xzB0, xnB0, xrB1, xzB1, xnB1)
    GRU_STEP(1, xrB0, xzB0, xnB0, xrB1, xzB1, xnB1,
                xrA0, xzA0, xnA0, xrA1, xzA1, xnA1)
  }
}

// ---------- heads (0-511) + anchor (512-639) -----------------------------------
// heads writes mean_x WITHOUT the anchor subtraction (applied in chol_fin).
// d=4..7 diag/off are scattered DIRECTLY into the chol upper half (zeroed by
// gru tail blocks; stream order guarantees completion before this launch).
__global__ __launch_bounds__(384) void heads_kernel(
    const float* __restrict__ enc, const float* __restrict__ WheadT,
    const float* __restrict__ b_mz, const float* __restrict__ b_mx,
    const float* __restrict__ b_pz, const float* __restrict__ b_cx,
    float* __restrict__ out_meanz, float* __restrict__ out_meanx,
    float* __restrict__ out_covx, float* __restrict__ stage,
    float* __restrict__ chol, float* __restrict__ anchor,
    const float* __restrict__ W_mx) {
  int tid = threadIdx.x;
  if (blockIdx.x >= 512) {               // ---- anchor: block = (b,d)
    __shared__ float red[4];
    int bid = blockIdx.x - 512;
    int b = bid >> 1, d = bid & 1;
    if (tid < 256) {
      float v = enc[(size_t)b * (T_ * H_) + tid] * W_mx[d * 256 + tid];
#pragma unroll
      for (int off = 32; off >= 1; off >>= 1) v += __shfl_down(v, off, 64);
      if ((tid & 63) == 0) red[tid >> 6] = v;
    }
    __syncthreads();
    if (tid == 0)
      anchor[b * 2 + d] = b_mx[d] + ((red[0] + red[1]) + (red[2] + red[3]));
    return;
  }
  __shared__ float el[32 * 256];         // 32 KB
  int row0 = blockIdx.x * 32;
  const float4* e4 = (const float4*)(enc + (size_t)row0 * 256);
  float4* el4 = (float4*)el;
#pragma unroll
  for (int i = 0; i < 6; ++i) {
    int idx = i * 384 + tid;             // 2048 float4 = 32x64
    if (idx < 2048) el4[idx] = e4[idx];
  }
  __syncthreads();
  int rg = tid / 96, c = tid - rg * 96;  // rg in [0,4), c in [0,96)
  const float4* Wc = (const float4*)(WheadT + c * 256);
  float acc[8];
#pragma unroll
  for (int r = 0; r < 8; ++r) acc[r] = 0.f;
  for (int k4 = 0; k4 < 64; ++k4) {
    float4 w4 = Wc[k4];
#pragma unroll
    for (int r = 0; r < 8; ++r) {
      float4 ev = el4[(rg * 8 + r) * 64 + k4];
      acc[r] += w4.x * ev.x; acc[r] += w4.y * ev.y;
      acc[r] += w4.z * ev.z; acc[r] += w4.w * ev.w;
    }
  }
#pragma unroll
  for (int r = 0; r < 8; ++r) {
    int row = row0 + rg * 8 + r;
    float a_ = acc[r];
    if (c < 8) {
      out_meanz[(size_t)row * 8 + c] = a_ + b_mz[c];
    } else if (c < 16) {
      int d = c - 8;
      out_meanx[(size_t)row * 8 + d] = a_ + b_mx[d];   // anchor applied later
    } else if (c < 32) {
      int d = c - 16;
      float v = a_ + b_pz[d];
      if (d < 8)                          // diag: softplus (stable)
        v = (v > 0.f) ? (v + log1pf(__expf(-v))) : log1pf(__expf(v));
      int bb = row >> 8, tt = row & 255;
      if (d < 4) {
        stage[(size_t)row * 16 + d] = v;              // lower diag -> chol_fin
      } else if (d < 8) {                             // upper diag: direct
        chol[(((size_t)d * 64 + bb) * 256 + tt) * 256 + tt] = v;
      } else if (d < 12) {
        stage[(size_t)row * 16 + d] = v;              // lower off -> chol_fin
      } else {                                        // upper off: direct
        int dd = d - 8;
        if (tt < 255)
          chol[(((size_t)dd * 64 + bb) * 256 + tt) * 256 + tt + 1] = v;
      }
    } else {
      int d = c - 32;
      out_covx[(size_t)row * 64 + d] = a_ + b_cx[d];
    }
  }
}

// ---------- final: fused zero+scatter lower chol + mean_x anchor fix ----------
__global__ __launch_bounds__(256) void chol_fin(
    const float* __restrict__ stage, float4* __restrict__ chol,
    const float* __restrict__ anchor, float* __restrict__ mean_x) {
  int i = blockIdx.x * 256 + threadIdx.x;
  int stride = gridDim.x * 256;
  for (; i < 4227072; i += stride) {
    if (i < 4194304) {                  // lower half: d = 0..3, fused zero+scatter
      int d = i >> 20;
      int bt = (i >> 6) & 16383;
      int t = bt & 255;
      int lane = i & 63;
      float vd = 0.f, vo = 0.f;
      if ((t >> 2) == lane)       vd = stage[bt * 16 + d];
      if (((t + 1) >> 2) == lane) vo = stage[bt * 16 + 8 + d];
      int te = t & 3, oe = (t + 1) & 3;
      float4 v;
      v.x = (te == 0 ? vd : 0.f) + (oe == 0 ? vo : 0.f);
      v.y = (te == 1 ? vd : 0.f) + (oe == 1 ? vo : 0.f);
      v.z = (te == 2 ? vd : 0.f) + (oe == 2 ? vo : 0.f);
      v.w = (te == 3 ? vd : 0.f) + (oe == 3 ? vo : 0.f);
      chol[i] = v;
    } else {                            // deferred anchor subtraction on mean_x
      int j2 = i - 4194304;             // [0, 32768)
      int row = j2 >> 1, d = j2 & 1;
      mean_x[(size_t)row * 8 + d] -= anchor[(row >> 8) * 2 + d];
    }
  }
}

extern "C" void kernel_launch(void* const* d_in, const int* in_sizes, int n_in,
                              void* d_out, int out_size, void* d_ws, size_t ws_size,
                              hipStream_t stream) {
  const float* y    = (const float*)d_in[0];
  const float* W_ih = (const float*)d_in[1];
  const float* W_hh = (const float*)d_in[2];
  const float* b_ih = (const float*)d_in[3];
  const float* b_hh = (const float*)d_in[4];
  const float* W_mz = (const float*)d_in[5];
  const float* b_mz = (const float*)d_in[6];
  const float* W_mx = (const float*)d_in[7];
  const float* b_mx = (const float*)d_in[8];
  const float* W_pz = (const float*)d_in[9];
  const float* b_pz = (const float*)d_in[10];
  const float* W_cx = (const float*)d_in[11];
  const float* b_cx = (const float*)d_in[12];

  float* out    = (float*)d_out;
  float* mean_z = out;                    // [64,256,8]
  float* chol   = out + 131072;           // [8,64,256,256]
  float* mean_x = out + 33685504;         // [16384,8]
  float* cov_x  = out + 33816576;         // [16384,8,8]

  float* ws      = (float*)d_ws;
  float* WT_ih   = ws;                    // 98304
  float* WheadT  = ws + 98304;            // 24576
  unsigned* Wreg = (unsigned*)(ws + 122880); // 98304
  float* anchor  = ws + 221184;           // 128
  float* stage   = ws + 221312;           // 262144

  // large scratch inside the chol LOWER half (rewritten by chol_fin at end);
  // upper half [16777216,33554432) is zeroed by gru tail blocks (overlapped).
  float* xp  = chol;                      // 12582912 floats
  float* enc = chol + 12582912;           // 4194304 floats (ends at 16777216)

  prep_kernel<<<864, 256, 0, stream>>>(W_ih, W_hh, W_mz, W_mx, W_pz, W_cx,
                                       WT_ih, WheadT, Wreg);
  xproj_kernel<<<512, 256, 0, stream>>>(y, WT_ih, b_ih, b_hh, xp);
  gru_kernel<<<256, 512, 0, stream>>>(xp, Wreg, b_hh, enc,
                                      ((float4*)chol) + 4194304);
  heads_kernel<<<640, 384, 0, stream>>>(enc, WheadT, b_mz, b_mx, b_pz, b_cx,
                                        mean_z, mean_x, cov_x, stage,
                                        chol, anchor, W_mx);
  chol_fin<<<4096, 256, 0, stream>>>(stage, (float4*)chol, anchor, mean_x);
}

// Round 3
// 545.967 us; speedup vs baseline: 1.0979x; 1.0218x over previous
//
#include <hip/hip_runtime.h>
#include <cstdint>
#include <cstddef>

#define B_   64
#define T_   256
#define DIN_ 128
#define H_   256
#define G3_  768   // 3*H

typedef _Float16 f16x8 __attribute__((ext_vector_type(8)));
typedef float    f32x4 __attribute__((ext_vector_type(4)));

#define MFMA(a, b, c) __builtin_amdgcn_mfma_f32_16x16x32_f16((a), (b), (c), 0, 0, 0)

// ---------- helpers ----------
__device__ __forceinline__ unsigned short f2h(float f) {
  _Float16 h = (_Float16)f;              // v_cvt_f16_f32 (RNE)
  return __builtin_bit_cast(unsigned short, h);
}

// ---------- prep ----------
// Wreg layout for 16-wave MFMA gru (1024 threads/block):
//   frag index fi = g*8 + kf   (g=gate 0..2, kf=K-frag 0..7)
//   thread tid: wave w=tid>>6, lane l=tid&63; output u = w*16 + (l&15)
//   B-frag dword d holds fp16 pair (k, k+1), k = kf*32 + (l>>4)*8 + 2d
//   Wreg dword m = (fi*1024 + tid)*4 + d -> coalesced uint4 loads W4[fi*1024+tid]
__global__ __launch_bounds__(256) void prep_kernel(
    const float* __restrict__ W_ih, const float* __restrict__ W_hh,
    const float* __restrict__ W_mz, const float* __restrict__ W_mx,
    const float* __restrict__ W_pz, const float* __restrict__ W_cx,
    float* __restrict__ WT_ih, float* __restrict__ WheadT,
    unsigned* __restrict__ Wreg) {
  int i = blockIdx.x * 256 + threadIdx.x;
  if (i < 98304) {                       // WT_ih[k*768+g] = W_ih[g*128+k]
    int k = i / 768, g = i % 768;
    WT_ih[i] = W_ih[g * 128 + k];
  } else if (i < 98304 + 24576) {        // WheadT[c*256+k]
    int j = i - 98304;
    int c = j >> 8, k = j & 255;
    float v;
    if (c < 8)       v = W_mz[c * 256 + k];
    else if (c < 16) v = W_mx[(c - 8) * 256 + k];
    else if (c < 32) v = W_pz[(c - 16) * 256 + k];
    else             v = W_cx[(c - 32) * 256 + k];
    WheadT[j] = v;
  } else {                               // W_hh fp16 B-frag repack (16-wave layout)
    int m = i - 122880;                  // 0..98303
    int d = m & 3, n = m >> 2;           // d = frag dword
    int tid = n & 1023, fi = n >> 10;    // fi in [0,24)
    int g  = fi >> 3, kf = fi & 7;
    int wv = tid >> 6, l = tid & 63;
    int u = wv * 16 + (l & 15);
    int k = kf * 32 + ((l >> 4) << 3) + 2 * d;
    int row = g * 256 + u;
    unsigned short lo = f2h(W_hh[row * 256 + k]);
    unsigned short hi = f2h(W_hh[row * 256 + k + 1]);
    Wreg[m] = ((unsigned)hi << 16) | (unsigned)lo;
  }
}

// ---------- x_proj = y @ W_ih^T + b_ih (+ b_hh folded for r,z gates) ----------
// 512 blocks: blockIdx>>1 selects 64-row stripe, blockIdx&1 selects 3 of 6 col-tiles.
__global__ __launch_bounds__(256) void xproj_kernel(
    const float* __restrict__ y, const float* __restrict__ WT_ih,
    const float* __restrict__ b_ih, const float* __restrict__ b_hh,
    float* __restrict__ xp) {
  __shared__ float ylds[64][132];
  int tid = threadIdx.x;
  int row0 = (blockIdx.x >> 1) * 64;
  int c0 = (blockIdx.x & 1) * 3;
  const float4* y4 = (const float4*)(y + (size_t)row0 * DIN_);
#pragma unroll
  for (int i = 0; i < 8; ++i) {
    int idx = i * 256 + tid;             // 2048 float4 = 64x128
    float4 v = y4[idx];
    int r = idx >> 5, c4 = (idx & 31) * 4;
    ylds[r][c4 + 0] = v.x; ylds[r][c4 + 1] = v.y;
    ylds[r][c4 + 2] = v.z; ylds[r][c4 + 3] = v.w;
  }
  __syncthreads();
  int tx = tid & 15, ty = tid >> 4;      // thread: 4 rows x 8 cols
  for (int c = c0; c < c0 + 3; ++c) {
    int col0 = c * 128 + tx * 8;
    float acc[4][8];
#pragma unroll
    for (int a = 0; a < 4; ++a)
#pragma unroll
      for (int b = 0; b < 8; ++b) acc[a][b] = 0.f;
#pragma unroll 4
    for (int k = 0; k < 128; ++k) {
      float4 w0 = *(const float4*)&WT_ih[k * 768 + col0];
      float4 w1 = *(const float4*)&WT_ih[k * 768 + col0 + 4];
      float a0 = ylds[ty * 4 + 0][k], a1 = ylds[ty * 4 + 1][k];
      float a2 = ylds[ty * 4 + 2][k], a3 = ylds[ty * 4 + 3][k];
      acc[0][0] += a0 * w0.x; acc[0][1] += a0 * w0.y; acc[0][2] += a0 * w0.z; acc[0][3] += a0 * w0.w;
      acc[0][4] += a0 * w1.x; acc[0][5] += a0 * w1.y; acc[0][6] += a0 * w1.z; acc[0][7] += a0 * w1.w;
      acc[1][0] += a1 * w0.x; acc[1][1] += a1 * w0.y; acc[1][2] += a1 * w0.z; acc[1][3] += a1 * w0.w;
      acc[1][4] += a1 * w1.x; acc[1][5] += a1 * w1.y; acc[1][6] += a1 * w1.z; acc[1][7] += a1 * w1.w;
      acc[2][0] += a2 * w0.x; acc[2][1] += a2 * w0.y; acc[2][2] += a2 * w0.z; acc[2][3] += a2 * w0.w;
      acc[2][4] += a2 * w1.x; acc[2][5] += a2 * w1.y; acc[2][6] += a2 * w1.z; acc[2][7] += a2 * w1.w;
      acc[3][0] += a3 * w0.x; acc[3][1] += a3 * w0.y; acc[3][2] += a3 * w0.z; acc[3][3] += a3 * w0.w;
      acc[3][4] += a3 * w1.x; acc[3][5] += a3 * w1.y; acc[3][6] += a3 * w1.z; acc[3][7] += a3 * w1.w;
    }
    float4 b0 = *(const float4*)&b_ih[col0];
    float4 b1 = *(const float4*)&b_ih[col0 + 4];
    if (c < 4) {                         // fold b_hh into r,z gate columns (<512)
      float4 h0 = *(const float4*)&b_hh[col0];
      float4 h1 = *(const float4*)&b_hh[col0 + 4];
      b0.x += h0.x; b0.y += h0.y; b0.z += h0.z; b0.w += h0.w;
      b1.x += h1.x; b1.y += h1.y; b1.z += h1.z; b1.w += h1.w;
    }
#pragma unroll
    for (int a = 0; a < 4; ++a) {
      int row = row0 + ty * 4 + a;
      float4 o0, o1;
      o0.x = acc[a][0] + b0.x; o0.y = acc[a][1] + b0.y; o0.z = acc[a][2] + b0.z; o0.w = acc[a][3] + b0.w;
      o1.x = acc[a][4] + b1.x; o1.y = acc[a][5] + b1.y; o1.z = acc[a][6] + b1.z; o1.w = acc[a][7] + b1.w;
      *(float4*)&xp[(size_t)row * G3_ + col0] = o0;
      *(float4*)&xp[(size_t)row * G3_ + col0 + 4] = o1;
    }
  }
}

// ---------- GRU recurrence via MFMA: blocks 0-63; blocks 64-159 zero chol upper --
// 16 waves x 64 lanes. Wave w owns outputs [16w, 16w+16) for all 3 gates:
// 24 B-frags = 96 weight VGPRs/thread -> fits the 128-VGPR budget that
// __launch_bounds__(1024) enforces (no AGPR operand shuttling).
// Lane l computes output u = 16w + (l&15); the 4 16-lane groups are replicas
// (A-operand = h replicated), group 0 writes. One barrier per step,
// double-buffered fp16 h in LDS.
__global__ __launch_bounds__(1024) void gru_kernel(
    const float* __restrict__ xp, const unsigned* __restrict__ Wreg,
    const float* __restrict__ b_hh, float* enc, float4* __restrict__ cholU) {
  int tid = threadIdx.x;
  int b = blockIdx.x;
  if (b >= 64) {                         // ---- tail blocks: zero chol upper half
    float4 zz = {0.f, 0.f, 0.f, 0.f};    //      (concurrent with the recurrence)
    int idx = (b - 64) * 1024 + tid;     // 96*1024 = 98304 threads
    for (; idx < 4194304; idx += 98304) cholU[idx] = zz;
    return;
  }
  int w = tid >> 6;
  int l = tid & 63;
  int g16 = l >> 4;                      // replica / K-chunk group
  int u = w * 16 + (l & 15);
  __shared__ alignas(16) unsigned short h16[2][256];   // double-buffered h

  f16x8 wfR[8], wfZ[8], wfN[8];          // W_hh B-frags, register-resident
  const uint4* W4 = (const uint4*)Wreg;
#pragma unroll
  for (int kf = 0; kf < 8; ++kf) {
    wfR[kf] = __builtin_bit_cast(f16x8, W4[(0 * 8 + kf) * 1024 + tid]);
    wfZ[kf] = __builtin_bit_cast(f16x8, W4[(1 * 8 + kf) * 1024 + tid]);
    wfN[kf] = __builtin_bit_cast(f16x8, W4[(2 * 8 + kf) * 1024 + tid]);
  }
  if (tid < 32) {                        // h0 = 0 (buffer 0 = first 32 uint4)
    uint4 z = {0u, 0u, 0u, 0u};
    ((uint4*)h16)[tid] = z;
  }
  const float* xpb = xp + (size_t)b * (T_ * G3_);
  float* encb = enc + (size_t)b * (T_ * H_);
  float bhn = b_hh[512 + u];
  float hold = 0.f;
  const f32x4 z4 = {0.f, 0.f, 0.f, 0.f};
  __syncthreads();
  const uint4* h4 = (const uint4*)h16;
  for (int t = 0; t < T_; ++t) {
    asm volatile("" ::: "memory");       // keep load placement per-step
    const float* xq = xpb + (size_t)t * G3_;
    // issue xp loads at step top; latency hides under the 24-MFMA body
    float xr = xq[u], xz = xq[256 + u], xn = xq[512 + u];
    int cur = t & 1;
    f32x4 aR, aZ, aN;
    {
      uint4 hq = h4[cur * 32 + g16];
      f16x8 hk = __builtin_bit_cast(f16x8, hq);
      aR = MFMA(hk, wfR[0], z4);
      aZ = MFMA(hk, wfZ[0], z4);
      aN = MFMA(hk, wfN[0], z4);
    }
#pragma unroll
    for (int kf = 1; kf < 8; ++kf) {
      uint4 hq = h4[cur * 32 + kf * 4 + g16];
      f16x8 hk = __builtin_bit_cast(f16x8, hq);
      aR = MFMA(hk, wfR[kf], aR);
      aZ = MFMA(hk, wfZ[kf], aZ);
      aN = MFMA(hk, wfN[kf], aN);
    }
    // r,z first so the sigmoid chain overlaps the tail of the N accumulate
    float pr = aR[0] + xr, pz = aZ[0] + xz;
    float r_ = 1.f / (1.f + __expf(-pr));
    float q_ = 1.f / (1.f + __expf(-pz));
    float zh = q_ * hold, om = 1.f - q_;
    float pn = aN[0] + bhn;
    float a = xn + r_ * pn;
    a = fminf(15.f, fmaxf(-15.f, a));
    float e = __expf(2.f * a);
    float n = (e - 1.f) / (e + 1.f);     // tanh
    float hn = om * n + zh;
    hold = hn;                           // exact fp32 state (replicated lanes)
    if (g16 == 0) {                      // one writer replica per wave
      encb[t * 256 + u] = hn;
      h16[cur ^ 1][u] = f2h(hn);
    }
    __syncthreads();                     // new h visible to all waves
  }
}

// ---------- heads (0-511) + anchor (512-639) -----------------------------------
// heads writes mean_x WITHOUT the anchor subtraction (applied in chol_fin).
// d=4..7 diag/off are scattered DIRECTLY into the chol upper half (zeroed by
// gru tail blocks; stream order guarantees completion before this launch).
__global__ __launch_bounds__(384) void heads_kernel(
    const float* __restrict__ enc, const float* __restrict__ WheadT,
    const float* __restrict__ b_mz, const float* __restrict__ b_mx,
    const float* __restrict__ b_pz, const float* __restrict__ b_cx,
    float* __restrict__ out_meanz, float* __restrict__ out_meanx,
    float* __restrict__ out_covx, float* __restrict__ stage,
    float* __restrict__ chol, float* __restrict__ anchor,
    const float* __restrict__ W_mx) {
  int tid = threadIdx.x;
  if (blockIdx.x >= 512) {               // ---- anchor: block = (b,d)
    __shared__ float red[4];
    int bid = blockIdx.x - 512;
    int b = bid >> 1, d = bid & 1;
    if (tid < 256) {
      float v = enc[(size_t)b * (T_ * H_) + tid] * W_mx[d * 256 + tid];
#pragma unroll
      for (int off = 32; off >= 1; off >>= 1) v += __shfl_down(v, off, 64);
      if ((tid & 63) == 0) red[tid >> 6] = v;
    }
    __syncthreads();
    if (tid == 0)
      anchor[b * 2 + d] = b_mx[d] + ((red[0] + red[1]) + (red[2] + red[3]));
    return;
  }
  __shared__ float el[32 * 256];         // 32 KB
  int row0 = blockIdx.x * 32;
  const float4* e4 = (const float4*)(enc + (size_t)row0 * 256);
  float4* el4 = (float4*)el;
#pragma unroll
  for (int i = 0; i < 6; ++i) {
    int idx = i * 384 + tid;             // 2048 float4 = 32x64
    if (idx < 2048) el4[idx] = e4[idx];
  }
  __syncthreads();
  int rg = tid / 96, c = tid - rg * 96;  // rg in [0,4), c in [0,96)
  const float4* Wc = (const float4*)(WheadT + c * 256);
  float acc[8];
#pragma unroll
  for (int r = 0; r < 8; ++r) acc[r] = 0.f;
  for (int k4 = 0; k4 < 64; ++k4) {
    float4 w4 = Wc[k4];
#pragma unroll
    for (int r = 0; r < 8; ++r) {
      float4 ev = el4[(rg * 8 + r) * 64 + k4];
      acc[r] += w4.x * ev.x; acc[r] += w4.y * ev.y;
      acc[r] += w4.z * ev.z; acc[r] += w4.w * ev.w;
    }
  }
#pragma unroll
  for (int r = 0; r < 8; ++r) {
    int row = row0 + rg * 8 + r;
    float a_ = acc[r];
    if (c < 8) {
      out_meanz[(size_t)row * 8 + c] = a_ + b_mz[c];
    } else if (c < 16) {
      int d = c - 8;
      out_meanx[(size_t)row * 8 + d] = a_ + b_mx[d];   // anchor applied later
    } else if (c < 32) {
      int d = c - 16;
      float v = a_ + b_pz[d];
      if (d < 8)                          // diag: softplus (stable)
        v = (v > 0.f) ? (v + log1pf(__expf(-v))) : log1pf(__expf(v));
      int bb = row >> 8, tt = row & 255;
      if (d < 4) {
        stage[(size_t)row * 16 + d] = v;              // lower diag -> chol_fin
      } else if (d < 8) {                             // upper diag: direct
        chol[(((size_t)d * 64 + bb) * 256 + tt) * 256 + tt] = v;
      } else if (d < 12) {
        stage[(size_t)row * 16 + d] = v;              // lower off -> chol_fin
      } else {                                        // upper off: direct
        int dd = d - 8;
        if (tt < 255)
          chol[(((size_t)dd * 64 + bb) * 256 + tt) * 256 + tt + 1] = v;
      }
    } else {
      int d = c - 32;
      out_covx[(size_t)row * 64 + d] = a_ + b_cx[d];
    }
  }
}

// ---------- final: fused zero+scatter lower chol + mean_x anchor fix ----------
__global__ __launch_bounds__(256) void chol_fin(
    const float* __restrict__ stage, float4* __restrict__ chol,
    const float* __restrict__ anchor, float* __restrict__ mean_x) {
  int i = blockIdx.x * 256 + threadIdx.x;
  int stride = gridDim.x * 256;
  for (; i < 4227072; i += stride) {
    if (i < 4194304) {                  // lower half: d = 0..3, fused zero+scatter
      int d = i >> 20;
      int bt = (i >> 6) & 16383;
      int t = bt & 255;
      int lane = i & 63;
      float vd = 0.f, vo = 0.f;
      if ((t >> 2) == lane)       vd = stage[bt * 16 + d];
      if (((t + 1) >> 2) == lane) vo = stage[bt * 16 + 8 + d];
      int te = t & 3, oe = (t + 1) & 3;
      float4 v;
      v.x = (te == 0 ? vd : 0.f) + (oe == 0 ? vo : 0.f);
      v.y = (te == 1 ? vd : 0.f) + (oe == 1 ? vo : 0.f);
      v.z = (te == 2 ? vd : 0.f) + (oe == 2 ? vo : 0.f);
      v.w = (te == 3 ? vd : 0.f) + (oe == 3 ? vo : 0.f);
      chol[i] = v;
    } else {                            // deferred anchor subtraction on mean_x
      int j2 = i - 4194304;             // [0, 32768)
      int row = j2 >> 1, d = j2 & 1;
      mean_x[(size_t)row * 8 + d] -= anchor[(row >> 8) * 2 + d];
    }
  }
}

extern "C" void kernel_launch(void* const* d_in, const int* in_sizes, int n_in,
                              void* d_out, int out_size, void* d_ws, size_t ws_size,
                              hipStream_t stream) {
  const float* y    = (const float*)d_in[0];
  const float* W_ih = (const float*)d_in[1];
  const float* W_hh = (const float*)d_in[2];
  const float* b_ih = (const float*)d_in[3];
  const float* b_hh = (const float*)d_in[4];
  const float* W_mz = (const float*)d_in[5];
  const float* b_mz = (const float*)d_in[6];
  const float* W_mx = (const float*)d_in[7];
  const float* b_mx = (const float*)d_in[8];
  const float* W_pz = (const float*)d_in[9];
  const float* b_pz = (const float*)d_in[10];
  const float* W_cx = (const float*)d_in[11];
  const float* b_cx = (const float*)d_in[12];

  float* out    = (float*)d_out;
  float* mean_z = out;                    // [64,256,8]
  float* chol   = out + 131072;           // [8,64,256,256]
  float* mean_x = out + 33685504;         // [16384,8]
  float* cov_x  = out + 33816576;         // [16384,8,8]

  float* ws      = (float*)d_ws;
  float* WT_ih   = ws;                    // 98304
  float* WheadT  = ws + 98304;            // 24576
  unsigned* Wreg = (unsigned*)(ws + 122880); // 98304
  float* anchor  = ws + 221184;           // 128
  float* stage   = ws + 221312;           // 262144

  // large scratch inside the chol LOWER half (rewritten by chol_fin at end);
  // upper half [16777216,33554432) is zeroed by gru tail blocks (overlapped).
  float* xp  = chol;                      // 12582912 floats
  float* enc = chol + 12582912;           // 4194304 floats (ends at 16777216)

  prep_kernel<<<864, 256, 0, stream>>>(W_ih, W_hh, W_mz, W_mx, W_pz, W_cx,
                                       WT_ih, WheadT, Wreg);
  xproj_kernel<<<512, 256, 0, stream>>>(y, WT_ih, b_ih, b_hh, xp);
  gru_kernel<<<160, 1024, 0, stream>>>(xp, Wreg, b_hh, enc,
                                       ((float4*)chol) + 4194304);
  heads_kernel<<<640, 384, 0, stream>>>(enc, WheadT, b_mz, b_mx, b_pz, b_cx,
                                        mean_z, mean_x, cov_x, stage,
                                        chol, anchor, W_mx);
  chol_fin<<<4096, 256, 0, stream>>>(stage, (float4*)chol, anchor, mean_x);
}